// Round 7
// baseline (55.067 us; speedup 1.0000x reference)
//
#include <hip/hip_runtime.h>

typedef float f4 __attribute__((ext_vector_type(4)));

// ---- constants matching the reference ----
#define NORMC 27353.34765625f
#define ALPHA_C 0.0257f
#define SRC_INTENSITY (100000.0f / NORMC)
#define FIRE_THRESHOLD (980.0f / NORMC)

constexpr int Wd = 128, Hd = 128, Dd = 64, Bd = 16;
constexpr int W4 = Wd / 4;            // 32 float4 per row
constexpr int HW4 = (Hd * Wd) / 4;    // 4096 float4 per z-plane
constexpr long long NTOT = (long long)Bd * Dd * Hd * Wd;  // 16777216
constexpr int N4 = (int)(NTOT / 4);   // 4194304
constexpr int NBLK = 2048;
constexpr int NTH = 256;
constexpr int STRIDE4 = NBLK * NTH;   // 524288
constexpr int NITER = N4 / STRIDE4;   // exactly 8

__device__ __forceinline__ f4 ldg4(const float* p) { return *(const f4*)p; }

__global__ __launch_bounds__(NTH) void loss_main(
    const float* __restrict__ in,
    const float* __restrict__ outc,
    const float* __restrict__ outp,
    const float* __restrict__ tvec,
    const float* __restrict__ tpvec,
    const float* __restrict__ tgt,
    float2* __restrict__ partial)
{
    const int tid = threadIdx.x;

    // chunked XCD swizzle (bijective: 2048 % 8 == 0). Consecutive sbid values
    // (which share y±1 and z±16 input halo lines) stay on ONE XCD's L2.
    const int bid  = blockIdx.x;
    const int sbid = (bid & 7) * (NBLK / 8) + (bid >> 3);
    const int base = sbid * NTH + tid;

    const int x4     = tid & (W4 - 1);   // invariant across k (strides are %32==0)
    const bool xl_ok = (x4 > 0);
    const bool xr_ok = (x4 < W4 - 1);

    float sp = 0.0f;   // sum residual^2
    float sm = 0.0f;   // sum (out - target)^2

    #pragma unroll
    for (int k = 0; k < NITER; ++k) {
        const int i4  = base + k * STRIDE4;
        const int idx = i4 << 2;
        const int y   = (i4 >> 5) & (Hd - 1);
        const int z   = (i4 >> 12) & (Dd - 1);
        const int b   = i4 >> 18;

        const f4 zero4 = {0.f, 0.f, 0.f, 0.f};
        // 10 independent loads per group — no cross-dependencies, max MLP
        const f4 c  = ldg4(in + idx);
        const f4 ym = (y > 0)      ? ldg4(in + idx - Wd)         : zero4;
        const f4 yp = (y < Hd - 1) ? ldg4(in + idx + Wd)         : zero4;
        const f4 zm = (z > 0)      ? ldg4(in + idx - (HW4 << 2)) : zero4;
        const f4 zp = (z < Dd - 1) ? ldg4(in + idx + (HW4 << 2)) : zero4;
        const float xl = xl_ok ? in[idx - 1] : 0.0f;
        const float xr = xr_ok ? in[idx + 4] : 0.0f;
        const f4 o  = ldg4(outc + idx);
        const f4 op = ldg4(outp + idx);
        const f4 tg = ldg4(tgt  + idx);

        const float dt  = tvec[b] - tpvec[b];
        const float rdt = 1.0f / dt;          // dt = 1.0 here: exact

        const float lap0 = xl  + c.y + ym.x + yp.x + zm.x + zp.x - 6.0f * c.x;
        const float lap1 = c.x + c.z + ym.y + yp.y + zm.y + zp.y - 6.0f * c.y;
        const float lap2 = c.y + c.w + ym.z + yp.z + zm.z + zp.z - 6.0f * c.z;
        const float lap3 = c.z + xr  + ym.w + yp.w + zm.w + zp.w - 6.0f * c.w;

        const float src0 = (c.x > FIRE_THRESHOLD) ? SRC_INTENSITY : 0.0f;
        const float src1 = (c.y > FIRE_THRESHOLD) ? SRC_INTENSITY : 0.0f;
        const float src2 = (c.z > FIRE_THRESHOLD) ? SRC_INTENSITY : 0.0f;
        const float src3 = (c.w > FIRE_THRESHOLD) ? SRC_INTENSITY : 0.0f;

        const float r0 = (o.x - op.x) * rdt - ALPHA_C * lap0 - src0;
        const float r1 = (o.y - op.y) * rdt - ALPHA_C * lap1 - src1;
        const float r2 = (o.z - op.z) * rdt - ALPHA_C * lap2 - src2;
        const float r3 = (o.w - op.w) * rdt - ALPHA_C * lap3 - src3;
        sp += r0 * r0 + r1 * r1 + r2 * r2 + r3 * r3;

        const float m0 = o.x - tg.x, m1 = o.y - tg.y;
        const float m2 = o.z - tg.z, m3 = o.w - tg.w;
        sm += m0 * m0 + m1 * m1 + m2 * m2 + m3 * m3;
    }

    // wave reduction (width 64)
    #pragma unroll
    for (int off = 32; off > 0; off >>= 1) {
        sp += __shfl_down(sp, off);
        sm += __shfl_down(sm, off);
    }
    __shared__ float2 wsum[NTH / 64];
    const int lane = tid & 63;
    const int wid  = tid >> 6;
    if (lane == 0) wsum[wid] = make_float2(sp, sm);
    __syncthreads();
    if (tid == 0) {
        float ap = 0.0f, am = 0.0f;
        #pragma unroll
        for (int w = 0; w < NTH / 64; ++w) { ap += wsum[w].x; am += wsum[w].y; }
        partial[blockIdx.x] = make_float2(ap, am);
    }
}

__global__ __launch_bounds__(256) void loss_reduce(
    const float2* __restrict__ partial, float* __restrict__ out)
{
    double sp = 0.0, sm = 0.0;
    for (int i = threadIdx.x; i < NBLK; i += blockDim.x) {
        const float2 v = partial[i];
        sp += (double)v.x;
        sm += (double)v.y;
    }
    #pragma unroll
    for (int off = 32; off > 0; off >>= 1) {
        sp += __shfl_down(sp, off);
        sm += __shfl_down(sm, off);
    }
    __shared__ double wsp[4], wsm[4];
    const int lane = threadIdx.x & 63;
    const int wid  = threadIdx.x >> 6;
    if (lane == 0) { wsp[wid] = sp; wsm[wid] = sm; }
    __syncthreads();
    if (threadIdx.x == 0) {
        double tp = 0.0, tm = 0.0;
        #pragma unroll
        for (int w = 0; w < 4; ++w) { tp += wsp[w]; tm += wsm[w]; }
        const double invN = 1.0 / (double)NTOT;
        out[0] = (float)(tm * invN + tp * invN);   // mse + A * p_loss, A = 1
    }
}

extern "C" void kernel_launch(void* const* d_in, const int* in_sizes, int n_in,
                              void* d_out, int out_size, void* d_ws, size_t ws_size,
                              hipStream_t stream) {
    const float* in_   = (const float*)d_in[0];
    const float* out_  = (const float*)d_in[1];
    const float* outp_ = (const float*)d_in[2];
    const float* t_    = (const float*)d_in[3];
    const float* tp_   = (const float*)d_in[4];
    const float* tgt_  = (const float*)d_in[5];

    float2* partial = (float2*)d_ws;   // NBLK * 8 B = 16 KiB

    loss_main<<<NBLK, NTH, 0, stream>>>(in_, out_, outp_, t_, tp_, tgt_, partial);
    loss_reduce<<<1, 256, 0, stream>>>(partial, (float*)d_out);
}

// Round 8
// 47.809 us; speedup vs baseline: 1.1518x; 1.1518x over previous
//
#include <hip/hip_runtime.h>

typedef float f4 __attribute__((ext_vector_type(4)));

// ---- constants matching the reference ----
#define NORMC 27353.34765625f
#define ALPHA_C 0.0257f
#define SRC_INTENSITY (100000.0f / NORMC)
#define FIRE_THRESHOLD (980.0f / NORMC)

constexpr int Wd = 128, Hd = 128, Dd = 64, Bd = 16;
constexpr int W4 = Wd / 4;            // 32 float4 per row
constexpr int HWc = Hd * Wd;          // 16384 elems per z-plane
constexpr long long NTOT = (long long)Bd * Dd * Hd * Wd;  // 16777216
constexpr int N4 = (int)(NTOT / 4);   // 4194304
constexpr int NBLK = 2048;
constexpr int NTH = 256;
constexpr int STRIDE4 = NBLK * NTH;   // 524288
constexpr int NITER = N4 / STRIDE4;   // exactly 8

__device__ __forceinline__ f4 ldg4(const float* p) { return *(const f4*)p; }

__global__ __launch_bounds__(NTH) void loss_main(
    const float* __restrict__ in,
    const float* __restrict__ outc,
    const float* __restrict__ outp,
    const float* __restrict__ tvec,
    const float* __restrict__ tpvec,
    const float* __restrict__ tgt,
    float2* __restrict__ partial)
{
    // double-buffered center tile: a block's 256 float4 = 8 consecutive y-rows
    // (32 float4 each) of one z-plane. Interior y-neighbors come from here.
    __shared__ f4 cbuf[2][NTH];

    const int tid = threadIdx.x;

    // chunked XCD swizzle (bijective: 2048 % 8 == 0): halo-sharing neighbor
    // blocks (sbid±1 for y, sbid±16 for z) stay on one XCD's L2.
    const int bid  = blockIdx.x;
    const int sbid = (bid & 7) * (NBLK / 8) + (bid >> 3);
    const int base = sbid * NTH + tid;

    const int x4     = tid & (W4 - 1);     // 0..31, invariant across k
    const int row    = tid >> 5;           // 0..7,  y % 8 within block
    const bool xl_ok = (x4 > 0);
    const bool xr_ok = (x4 < W4 - 1);
    const bool top   = (row == 0);         // needs global y-1 halo
    const bool bot   = (row == 7);         // needs global y+1 halo

    float sp = 0.0f;   // sum residual^2
    float sm = 0.0f;   // sum (out - target)^2

    #pragma unroll 1
    for (int k = 0; k < NITER; ++k) {
        const int i4  = base + k * STRIDE4;
        const int idx = i4 << 2;
        const int y   = (i4 >> 5) & (Hd - 1);
        const int z   = (i4 >> 12) & (Dd - 1);
        const int b   = i4 >> 18;
        const int p   = k & 1;

        const f4 zero4 = {0.f, 0.f, 0.f, 0.f};
        // independent global loads (6 per thread + rare y-halo)
        const f4 c  = ldg4(in + idx);
        const f4 zm = (z > 0)      ? ldg4(in + idx - HWc) : zero4;
        const f4 zp = (z < Dd - 1) ? ldg4(in + idx + HWc) : zero4;
        const f4 o  = ldg4(outc + idx);
        const f4 op = ldg4(outp + idx);
        const f4 tg = ldg4(tgt  + idx);
        f4 yh_lo = zero4, yh_hi = zero4;
        if (top && y > 0)      yh_lo = ldg4(in + idx - Wd);
        if (bot && y < Hd - 1) yh_hi = ldg4(in + idx + Wd);

        // stage center tile; barrier publishes it block-wide.
        // WAR safety across iterations: double buffer + this barrier.
        cbuf[p][tid] = c;
        __syncthreads();

        const f4 ym = top ? yh_lo : cbuf[p][tid - 32];
        const f4 yp = bot ? yh_hi : cbuf[p][tid + 32];

        // x-neighbors from adjacent lanes (row = 32 lanes; boundaries masked)
        const float xls = __shfl_up(c.w, 1);
        const float xrs = __shfl_down(c.x, 1);
        const float xl  = xl_ok ? xls : 0.0f;
        const float xr  = xr_ok ? xrs : 0.0f;

        const float dt  = tvec[b] - tpvec[b];
        const float rdt = 1.0f / dt;          // dt = 1.0 here: exact

        const float lap0 = xl  + c.y + ym.x + yp.x + zm.x + zp.x - 6.0f * c.x;
        const float lap1 = c.x + c.z + ym.y + yp.y + zm.y + zp.y - 6.0f * c.y;
        const float lap2 = c.y + c.w + ym.z + yp.z + zm.z + zp.z - 6.0f * c.z;
        const float lap3 = c.z + xr  + ym.w + yp.w + zm.w + zp.w - 6.0f * c.w;

        const float src0 = (c.x > FIRE_THRESHOLD) ? SRC_INTENSITY : 0.0f;
        const float src1 = (c.y > FIRE_THRESHOLD) ? SRC_INTENSITY : 0.0f;
        const float src2 = (c.z > FIRE_THRESHOLD) ? SRC_INTENSITY : 0.0f;
        const float src3 = (c.w > FIRE_THRESHOLD) ? SRC_INTENSITY : 0.0f;

        const float r0 = (o.x - op.x) * rdt - ALPHA_C * lap0 - src0;
        const float r1 = (o.y - op.y) * rdt - ALPHA_C * lap1 - src1;
        const float r2 = (o.z - op.z) * rdt - ALPHA_C * lap2 - src2;
        const float r3 = (o.w - op.w) * rdt - ALPHA_C * lap3 - src3;
        sp += r0 * r0 + r1 * r1 + r2 * r2 + r3 * r3;

        const float m0 = o.x - tg.x, m1 = o.y - tg.y;
        const float m2 = o.z - tg.z, m3 = o.w - tg.w;
        sm += m0 * m0 + m1 * m1 + m2 * m2 + m3 * m3;
    }

    // wave reduction (width 64)
    #pragma unroll
    for (int off = 32; off > 0; off >>= 1) {
        sp += __shfl_down(sp, off);
        sm += __shfl_down(sm, off);
    }
    __shared__ float2 wsum[NTH / 64];
    const int lane = tid & 63;
    const int wid  = tid >> 6;
    if (lane == 0) wsum[wid] = make_float2(sp, sm);
    __syncthreads();
    if (tid == 0) {
        float ap = 0.0f, am = 0.0f;
        #pragma unroll
        for (int w = 0; w < NTH / 64; ++w) { ap += wsum[w].x; am += wsum[w].y; }
        partial[blockIdx.x] = make_float2(ap, am);
    }
}

__global__ __launch_bounds__(256) void loss_reduce(
    const float2* __restrict__ partial, float* __restrict__ out)
{
    double sp = 0.0, sm = 0.0;
    for (int i = threadIdx.x; i < NBLK; i += blockDim.x) {
        const float2 v = partial[i];
        sp += (double)v.x;
        sm += (double)v.y;
    }
    #pragma unroll
    for (int off = 32; off > 0; off >>= 1) {
        sp += __shfl_down(sp, off);
        sm += __shfl_down(sm, off);
    }
    __shared__ double wsp[4], wsm[4];
    const int lane = threadIdx.x & 63;
    const int wid  = threadIdx.x >> 6;
    if (lane == 0) { wsp[wid] = sp; wsm[wid] = sm; }
    __syncthreads();
    if (threadIdx.x == 0) {
        double tp = 0.0, tm = 0.0;
        #pragma unroll
        for (int w = 0; w < 4; ++w) { tp += wsp[w]; tm += wsm[w]; }
        const double invN = 1.0 / (double)NTOT;
        out[0] = (float)(tm * invN + tp * invN);   // mse + A * p_loss, A = 1
    }
}

extern "C" void kernel_launch(void* const* d_in, const int* in_sizes, int n_in,
                              void* d_out, int out_size, void* d_ws, size_t ws_size,
                              hipStream_t stream) {
    const float* in_   = (const float*)d_in[0];
    const float* out_  = (const float*)d_in[1];
    const float* outp_ = (const float*)d_in[2];
    const float* t_    = (const float*)d_in[3];
    const float* tp_   = (const float*)d_in[4];
    const float* tgt_  = (const float*)d_in[5];

    float2* partial = (float2*)d_ws;   // NBLK * 8 B = 16 KiB

    loss_main<<<NBLK, NTH, 0, stream>>>(in_, out_, outp_, t_, tp_, tgt_, partial);
    loss_reduce<<<1, 256, 0, stream>>>(partial, (float*)d_out);
}